// Round 3
// baseline (363.142 us; speedup 1.0000x reference)
//
#include <hip/hip_runtime.h>
#include <hip/hip_bf16.h>
#include <math.h>

typedef short bf16x8 __attribute__((ext_vector_type(8)));
typedef float f32x4 __attribute__((ext_vector_type(4)));

#if __has_builtin(__builtin_amdgcn_exp2f)
#define EXP2F(x) __builtin_amdgcn_exp2f(x)
#else
#define EXP2F(x) __expf(0.69314718056f * (x))
#endif

__device__ __forceinline__ unsigned short f2bf(float f) {
    union { float f; unsigned u; } v; v.f = f;
    unsigned r = v.u + 0x7fffu + ((v.u >> 16) & 1u);   // RNE
    return (unsigned short)(r >> 16);
}

__device__ __forceinline__ unsigned pack_bf2(float a, float b) {
    __hip_bfloat162 h = __float22bfloat162_rn(float2{a, b});
    union { __hip_bfloat162 h; unsigned u; } c; c.h = h;
    return c.u;
}

__device__ __forceinline__ void gld_lds16(const unsigned short* g, const unsigned short* l) {
    __builtin_amdgcn_global_load_lds(
        (const __attribute__((address_space(1))) void*)g,
        (__attribute__((address_space(3))) void*)l, 16, 0, 0);
}

// ---------- fp32 -> bf16 converts ----------
__global__ void cvt_f32_bf16(const float* __restrict__ src, unsigned short* __restrict__ dst, int n) {
    int i = (blockIdx.x * blockDim.x + threadIdx.x) * 4;
    if (i < n) {
        float4 f = *(const float4*)(src + i);
        ushort4 o;
        o.x = f2bf(f.x); o.y = f2bf(f.y); o.z = f2bf(f.z); o.w = f2bf(f.w);
        *(ushort4*)(dst + i) = o;
    }
}

__global__ void cvt4_f32_bf16(const float* s0, const float* s1, const float* s2, const float* s3,
                              unsigned short* d0, unsigned short* d1, unsigned short* d2,
                              unsigned short* d3, int n) {
    const float* s; unsigned short* d;
    switch (blockIdx.y) {
        case 0: s = s0; d = d0; break;
        case 1: s = s1; d = d1; break;
        case 2: s = s2; d = d2; break;
        default: s = s3; d = d3; break;
    }
    int i = (blockIdx.x * blockDim.x + threadIdx.x) * 4;
    if (i < n) {
        float4 f = *(const float4*)(s + i);
        ushort4 o;
        o.x = f2bf(f.x); o.y = f2bf(f.y); o.z = f2bf(f.z); o.w = f2bf(f.w);
        *(ushort4*)(d + i) = o;
    }
}

// ---------- GEMM: C[M,Nlog] = A[M,K] @ W[Nlog,K]^T + bias ----------
// Nlog can be 3072 (fused QKV): output buffer = col>>10 (stride BUFS), col&1023
// within; bias pointer selected per block by buffer. 128x128 tile, 4 waves,
// BK=32, global_load_lds width-16 staging.
__global__ __launch_bounds__(256) void gemm_bt(
        const unsigned short* __restrict__ A, const unsigned short* __restrict__ W,
        const float* __restrict__ b0p, const float* __restrict__ b1p,
        const float* __restrict__ b2p, float* __restrict__ outF,
        unsigned short* __restrict__ outB, int M, int Nlog, int K) {
    __shared__ __align__(16) unsigned short As[128][32];
    __shared__ __align__(16) unsigned short Ws[128][32];
    const size_t BUFS = (size_t)8192 * 1024;
    const int m0 = blockIdx.y * 128, n0 = blockIdx.x * 128;
    const int tid = threadIdx.x, lane = tid & 63, w = tid >> 6;
    const int quad = lane >> 4, lc = lane & 15;
    const int wr = (w >> 1) * 64, wc = (w & 1) * 64;
    const int sr = lane >> 2, sc = (lane & 3) * 8;

    const int buf = n0 >> 10;
    const float* bias = buf == 0 ? b0p : (buf == 1 ? b1p : b2p);

    f32x4 acc[4][4] = {};

    for (int k0 = 0; k0 < K; k0 += 32) {
        __syncthreads();
        gld_lds16(A + (size_t)(m0 + w * 32 +      sr) * K + k0 + sc, &As[w * 32     ][0]);
        gld_lds16(A + (size_t)(m0 + w * 32 + 16 + sr) * K + k0 + sc, &As[w * 32 + 16][0]);
        gld_lds16(W + (size_t)(n0 + w * 32 +      sr) * K + k0 + sc, &Ws[w * 32     ][0]);
        gld_lds16(W + (size_t)(n0 + w * 32 + 16 + sr) * K + k0 + sc, &Ws[w * 32 + 16][0]);
        __syncthreads();
        bf16x8 af[4], bw[4];
        #pragma unroll
        for (int i = 0; i < 4; ++i) af[i] = *(const bf16x8*)&As[wr + i * 16 + lc][quad * 8];
        #pragma unroll
        for (int j = 0; j < 4; ++j) bw[j] = *(const bf16x8*)&Ws[wc + j * 16 + lc][quad * 8];
        #pragma unroll
        for (int i = 0; i < 4; ++i)
            #pragma unroll
            for (int j = 0; j < 4; ++j)
                acc[i][j] = __builtin_amdgcn_mfma_f32_16x16x32_bf16(af[i], bw[j], acc[i][j], 0, 0, 0);
    }

    #pragma unroll
    for (int j = 0; j < 4; ++j) {
        int col = n0 + wc + j * 16 + lc;
        int coll = col & 1023;
        float bj = bias[coll];
        #pragma unroll
        for (int i = 0; i < 4; ++i) {
            int rowb = m0 + wr + i * 16 + quad * 4;
            #pragma unroll
            for (int r = 0; r < 4; ++r) {
                float v = acc[i][j][r] + bj;
                size_t idx = (size_t)buf * BUFS + (size_t)(rowb + r) * 1024 + coll;
                if (outB) outB[idx] = f2bf(v);
                else      outF[idx] = v;
            }
        }
    }
}

// ---------- flash attention (S^T / O^T formulation, exp2 domain) ----------
// One q-tile per block, heavy-first dispatch (qt = 31 - blockIdx.x).
// Per wave: 16 q rows (q = lc). Off-diagonal k-tiles skip the causal test.
__global__ __launch_bounds__(256, 5) void attn_kernel(
        const unsigned short* __restrict__ Q, const unsigned short* __restrict__ K,
        const unsigned short* __restrict__ V, const int* __restrict__ tmask,
        unsigned short* __restrict__ O) {
    const int T = 2048, C = 1024;
    __shared__ __align__(16) unsigned short Kl[64][72];
    __shared__ __align__(16) unsigned short VT[64][72];
    __shared__ __align__(16) unsigned short Pl[4][16][72];
    __shared__ float maskf[64];

    const int qt = 31 - blockIdx.x;       // heavy-first
    const int bn = blockIdx.y;
    const int b = bn >> 4, h = bn & 15;
    const int tid = threadIdx.x, w = tid >> 6, lane = tid & 63;
    const int quad = lane >> 4, lc = lane & 15;
    const float NEG_INF = -__builtin_inff();
    const float CSC = 0.18033688011112042f;   // 0.125 * log2(e)

    size_t qrow = (size_t)(b * T + qt * 64 + w * 16 + lc) * C + h * 64;
    bf16x8 qb0 = *(const bf16x8*)(Q + qrow + quad * 8);
    bf16x8 qb1 = *(const bf16x8*)(Q + qrow + 32 + quad * 8);

    f32x4 oaccT[4] = {};                  // [jd]: d = jd*16+quad*4+r, q = lc
    float m = NEG_INF, l = 0.f;
    const int qg = qt * 64 + w * 16 + lc;

    auto step = [&](int kt, bool DIAG) {
        __syncthreads();
        {   // K tile row-major
            int r = tid >> 2, c16 = (tid & 3) * 16;
            size_t g = (size_t)(b * T + kt * 64 + r) * C + h * 64 + c16;
            *(bf16x8*)&Kl[r][c16]     = *(const bf16x8*)(K + g);
            *(bf16x8*)&Kl[r][c16 + 8] = *(const bf16x8*)(K + g + 8);
        }
        {   // V transposed, packed pair-of-rows b32 writes
            int r0 = (tid & 31) * 2, c8 = (tid >> 5) * 8;
            size_t g = (size_t)(b * T + kt * 64 + r0) * C + h * 64 + c8;
            bf16x8 v0 = *(const bf16x8*)(V + g);
            bf16x8 v1 = *(const bf16x8*)(V + g + C);
            #pragma unroll
            for (int i = 0; i < 8; ++i) {
                unsigned pk = (unsigned short)v0[i] | ((unsigned)(unsigned short)v1[i] << 16);
                *(unsigned*)&VT[c8 + i][r0] = pk;
            }
        }
        if (tid < 64)
            maskf[tid] = tmask[b * T + kt * 64 + tid] ? 0.0f : NEG_INF;
        __syncthreads();

        // S^T = K Q^T
        f32x4 sacc[4] = {};
        #pragma unroll
        for (int j = 0; j < 4; ++j) {
            bf16x8 ka0 = *(const bf16x8*)&Kl[j * 16 + lc][quad * 8];
            bf16x8 ka1 = *(const bf16x8*)&Kl[j * 16 + lc][32 + quad * 8];
            sacc[j] = __builtin_amdgcn_mfma_f32_16x16x32_bf16(ka0, qb0, sacc[j], 0, 0, 0);
            sacc[j] = __builtin_amdgcn_mfma_f32_16x16x32_bf16(ka1, qb1, sacc[j], 0, 0, 0);
        }

        // t = sacc*CSC + mask (exp2 domain); causal only on diagonal tile
        float s[4][4];
        float mx = NEG_INF;
        #pragma unroll
        for (int j = 0; j < 4; ++j) {
            f32x4 mk = *(const f32x4*)&maskf[j * 16 + quad * 4];
            #pragma unroll
            for (int r = 0; r < 4; ++r) {
                float sv = fmaf(sacc[j][r], CSC, mk[r]);
                if (DIAG) {
                    int kg = kt * 64 + j * 16 + quad * 4 + r;
                    if (kg > qg) sv = NEG_INF;
                }
                s[j][r] = sv;
                mx = fmaxf(mx, sv);
            }
        }
        mx = fmaxf(mx, __shfl_xor(mx, 16, 64));
        mx = fmaxf(mx, __shfl_xor(mx, 32, 64));
        float mnew = fmaxf(m, mx);
        float alpha = EXP2F(m - mnew);
        m = mnew;
        float ps = 0.f;
        #pragma unroll
        for (int j = 0; j < 4; ++j)
            #pragma unroll
            for (int r = 0; r < 4; ++r) {
                float p = EXP2F(s[j][r] - mnew);
                s[j][r] = p;
                ps += p;
            }
        ps += __shfl_xor(ps, 16, 64);
        ps += __shfl_xor(ps, 32, 64);
        l = l * alpha + ps;
        #pragma unroll
        for (int jd = 0; jd < 4; ++jd) oaccT[jd] *= alpha;

        // P rows to LDS via packed bf16 cvt (b64 writes)
        #pragma unroll
        for (int j = 0; j < 4; ++j) {
            uint2 pk;
            pk.x = pack_bf2(s[j][0], s[j][1]);
            pk.y = pack_bf2(s[j][2], s[j][3]);
            *(uint2*)&Pl[w][lc][j * 16 + quad * 4] = pk;
        }
        bf16x8 pb0 = *(const bf16x8*)&Pl[w][lc][quad * 8];
        bf16x8 pb1 = *(const bf16x8*)&Pl[w][lc][32 + quad * 8];

        // O^T += V^T P^T
        #pragma unroll
        for (int jd = 0; jd < 4; ++jd) {
            bf16x8 va0 = *(const bf16x8*)&VT[jd * 16 + lc][quad * 8];
            bf16x8 va1 = *(const bf16x8*)&VT[jd * 16 + lc][32 + quad * 8];
            oaccT[jd] = __builtin_amdgcn_mfma_f32_16x16x32_bf16(va0, pb0, oaccT[jd], 0, 0, 0);
            oaccT[jd] = __builtin_amdgcn_mfma_f32_16x16x32_bf16(va1, pb1, oaccT[jd], 0, 0, 0);
        }
    };

    #pragma unroll 1
    for (int kt = 0; kt < qt; ++kt) step(kt, false);
    step(qt, true);

    float inv = 1.0f / l;
    size_t orow = (size_t)(b * T + qt * 64 + w * 16 + lc) * C + h * 64;
    #pragma unroll
    for (int jd = 0; jd < 4; ++jd) {
        ushort4 o4;
        o4.x = f2bf(oaccT[jd][0] * inv);
        o4.y = f2bf(oaccT[jd][1] * inv);
        o4.z = f2bf(oaccT[jd][2] * inv);
        o4.w = f2bf(oaccT[jd][3] * inv);
        *(ushort4*)(O + orow + jd * 16 + quad * 4) = o4;
    }
}

extern "C" void kernel_launch(void* const* d_in, const int* in_sizes, int n_in,
                              void* d_out, int out_size, void* d_ws, size_t ws_size,
                              hipStream_t stream) {
    const float* x  = (const float*)d_in[0];
    const int* tm   = (const int*)d_in[1];
    const float* wq = (const float*)d_in[2]; const float* bq = (const float*)d_in[3];
    const float* wk = (const float*)d_in[4]; const float* bk = (const float*)d_in[5];
    const float* wv = (const float*)d_in[6]; const float* bv = (const float*)d_in[7];
    const float* wp = (const float*)d_in[8]; const float* bp = (const float*)d_in[9];
    float* out = (float*)d_out;

    const int Bv = 4, Tv = 2048, Cv = 1024;
    const size_t MT = (size_t)Bv * Tv;           // 8192 rows
    const size_t XN = MT * Cv;
    const size_t WN = (size_t)Cv * Cv;

    // layout (bf16): xb | wq wk wv (contiguous = fused 3072x1024) | wp | Q K V (contiguous)
    unsigned short* xb  = (unsigned short*)d_ws;
    unsigned short* wqb = xb  + XN;
    unsigned short* wkb = wqb + WN;
    unsigned short* wvb = wkb + WN;
    unsigned short* wpb = wvb + WN;
    unsigned short* Qb  = wpb + WN;
    unsigned short* Kb  = Qb + XN;
    unsigned short* Vb  = Kb + XN;
    unsigned short* Ab  = xb;                    // attn output reuses xb

    cvt_f32_bf16<<<XN / 1024, 256, 0, stream>>>(x, xb, (int)XN);
    cvt4_f32_bf16<<<dim3(WN / 1024, 4), 256, 0, stream>>>(wq, wk, wv, wp, wqb, wkb, wvb, wpb, (int)WN);

    // fused QKV: logical N = 3072, weight = [wqb;wkb;wvb], out buffers Qb/Kb/Vb
    gemm_bt<<<dim3(24, 64), 256, 0, stream>>>(xb, wqb, bq, bk, bv, nullptr, Qb, (int)MT, 3072, Cv);

    attn_kernel<<<dim3(32, Bv * 16), 256, 0, stream>>>(Qb, Kb, Vb, tm, Ab);

    gemm_bt<<<dim3(8, 64), 256, 0, stream>>>(Ab, wpb, bp, bp, bp, out, nullptr, (int)MT, 1024, Cv);
}

// Round 4
// 310.736 us; speedup vs baseline: 1.1686x; 1.1686x over previous
//
#include <hip/hip_runtime.h>
#include <hip/hip_bf16.h>
#include <math.h>

typedef short bf16x8 __attribute__((ext_vector_type(8)));
typedef float f32x4 __attribute__((ext_vector_type(4)));

#if __has_builtin(__builtin_amdgcn_exp2f)
#define EXP2F(x) __builtin_amdgcn_exp2f(x)
#else
#define EXP2F(x) __expf(0.69314718056f * (x))
#endif

__device__ __forceinline__ unsigned short f2bf(float f) {
    union { float f; unsigned u; } v; v.f = f;
    unsigned r = v.u + 0x7fffu + ((v.u >> 16) & 1u);   // RNE
    return (unsigned short)(r >> 16);
}

__device__ __forceinline__ unsigned pack_bf2(float a, float b) {
    __hip_bfloat162 h = __float22bfloat162_rn(float2{a, b});
    union { __hip_bfloat162 h; unsigned u; } c; c.h = h;
    return c.u;
}

__device__ __forceinline__ void gld_lds16(const unsigned short* g, const unsigned short* l) {
    __builtin_amdgcn_global_load_lds(
        (const __attribute__((address_space(1))) void*)g,
        (__attribute__((address_space(3))) void*)l, 16, 0, 0);
}

// ---------- fp32 -> bf16 converts ----------
__global__ void cvt_f32_bf16(const float* __restrict__ src, unsigned short* __restrict__ dst, int n) {
    int i = (blockIdx.x * blockDim.x + threadIdx.x) * 4;
    if (i < n) {
        float4 f = *(const float4*)(src + i);
        ushort4 o;
        o.x = f2bf(f.x); o.y = f2bf(f.y); o.z = f2bf(f.z); o.w = f2bf(f.w);
        *(ushort4*)(dst + i) = o;
    }
}

__global__ void cvt4_f32_bf16(const float* s0, const float* s1, const float* s2, const float* s3,
                              unsigned short* d0, unsigned short* d1, unsigned short* d2,
                              unsigned short* d3, int n) {
    const float* s; unsigned short* d;
    switch (blockIdx.y) {
        case 0: s = s0; d = d0; break;
        case 1: s = s1; d = d1; break;
        case 2: s = s2; d = d2; break;
        default: s = s3; d = d3; break;
    }
    int i = (blockIdx.x * blockDim.x + threadIdx.x) * 4;
    if (i < n) {
        float4 f = *(const float4*)(s + i);
        ushort4 o;
        o.x = f2bf(f.x); o.y = f2bf(f.y); o.z = f2bf(f.z); o.w = f2bf(f.w);
        *(ushort4*)(d + i) = o;
    }
}

// ---------- GEMM: C[M,Nlog] = A[M,K] @ W[Nlog,K]^T + bias ----------
// Nlog can be 3072 (fused QKV): output buffer = col>>10, bias selected per block.
__global__ __launch_bounds__(256) void gemm_bt(
        const unsigned short* __restrict__ A, const unsigned short* __restrict__ W,
        const float* __restrict__ b0p, const float* __restrict__ b1p,
        const float* __restrict__ b2p, float* __restrict__ outF,
        unsigned short* __restrict__ outB, int M, int Nlog, int K) {
    __shared__ __align__(16) unsigned short As[128][32];
    __shared__ __align__(16) unsigned short Ws[128][32];
    const size_t BUFS = (size_t)8192 * 1024;
    const int m0 = blockIdx.y * 128, n0 = blockIdx.x * 128;
    const int tid = threadIdx.x, lane = tid & 63, w = tid >> 6;
    const int quad = lane >> 4, lc = lane & 15;
    const int wr = (w >> 1) * 64, wc = (w & 1) * 64;
    const int sr = lane >> 2, sc = (lane & 3) * 8;

    const int buf = n0 >> 10;
    const float* bias = buf == 0 ? b0p : (buf == 1 ? b1p : b2p);

    f32x4 acc[4][4] = {};

    for (int k0 = 0; k0 < K; k0 += 32) {
        __syncthreads();
        gld_lds16(A + (size_t)(m0 + w * 32 +      sr) * K + k0 + sc, &As[w * 32     ][0]);
        gld_lds16(A + (size_t)(m0 + w * 32 + 16 + sr) * K + k0 + sc, &As[w * 32 + 16][0]);
        gld_lds16(W + (size_t)(n0 + w * 32 +      sr) * K + k0 + sc, &Ws[w * 32     ][0]);
        gld_lds16(W + (size_t)(n0 + w * 32 + 16 + sr) * K + k0 + sc, &Ws[w * 32 + 16][0]);
        __syncthreads();
        bf16x8 af[4], bw[4];
        #pragma unroll
        for (int i = 0; i < 4; ++i) af[i] = *(const bf16x8*)&As[wr + i * 16 + lc][quad * 8];
        #pragma unroll
        for (int j = 0; j < 4; ++j) bw[j] = *(const bf16x8*)&Ws[wc + j * 16 + lc][quad * 8];
        #pragma unroll
        for (int i = 0; i < 4; ++i)
            #pragma unroll
            for (int j = 0; j < 4; ++j)
                acc[i][j] = __builtin_amdgcn_mfma_f32_16x16x32_bf16(af[i], bw[j], acc[i][j], 0, 0, 0);
    }

    #pragma unroll
    for (int j = 0; j < 4; ++j) {
        int col = n0 + wc + j * 16 + lc;
        int coll = col & 1023;
        float bj = bias[coll];
        #pragma unroll
        for (int i = 0; i < 4; ++i) {
            int rowb = m0 + wr + i * 16 + quad * 4;
            #pragma unroll
            for (int r = 0; r < 4; ++r) {
                float v = acc[i][j][r] + bj;
                size_t idx = (size_t)buf * BUFS + (size_t)(rowb + r) * 1024 + coll;
                if (outB) outB[idx] = f2bf(v);
                else      outF[idx] = v;
            }
        }
    }
}

// ---------- flash attention (S^T / O^T, exp2 domain, paired q-tiles) ----------
// Blocks process q-tile pair (p, 31-p): exactly 33 steps each, 1024 uniform
// blocks = full residency at 4/CU, no tail. Off-diagonal k-tiles skip causal.
__global__ __launch_bounds__(256, 4) void attn_kernel(
        const unsigned short* __restrict__ Q, const unsigned short* __restrict__ K,
        const unsigned short* __restrict__ V, const int* __restrict__ tmask,
        unsigned short* __restrict__ O) {
    const int T = 2048, C = 1024;
    __shared__ __align__(16) unsigned short Kl[64][72];
    __shared__ __align__(16) unsigned short VT[64][72];
    __shared__ __align__(16) unsigned short Pl[4][16][72];
    __shared__ float maskf[64];

    const int pair = blockIdx.x;          // 0..15
    const int bn = blockIdx.y;
    const int b = bn >> 4, h = bn & 15;
    const int tid = threadIdx.x, w = tid >> 6, lane = tid & 63;
    const int quad = lane >> 4, lc = lane & 15;
    const float NEG_INF = -__builtin_inff();
    const float CSC = 0.18033688011112042f;   // 0.125 * log2(e)

    #pragma unroll 1
    for (int half = 0; half < 2; ++half) {
        const int qt = half ? (31 - pair) : pair;

        size_t qrow = (size_t)(b * T + qt * 64 + w * 16 + lc) * C + h * 64;
        bf16x8 qb0 = *(const bf16x8*)(Q + qrow + quad * 8);
        bf16x8 qb1 = *(const bf16x8*)(Q + qrow + 32 + quad * 8);

        f32x4 oaccT[4] = {};                  // [jd]: d = jd*16+quad*4+r, q = lc
        float m = NEG_INF, l = 0.f;
        const int qg = qt * 64 + w * 16 + lc;

        auto step = [&](int kt, bool DIAG) {
            __syncthreads();
            {   // K tile row-major
                int r = tid >> 2, c16 = (tid & 3) * 16;
                size_t g = (size_t)(b * T + kt * 64 + r) * C + h * 64 + c16;
                *(bf16x8*)&Kl[r][c16]     = *(const bf16x8*)(K + g);
                *(bf16x8*)&Kl[r][c16 + 8] = *(const bf16x8*)(K + g + 8);
            }
            {   // V transposed, packed pair-of-rows b32 writes
                int r0 = (tid & 31) * 2, c8 = (tid >> 5) * 8;
                size_t g = (size_t)(b * T + kt * 64 + r0) * C + h * 64 + c8;
                bf16x8 v0 = *(const bf16x8*)(V + g);
                bf16x8 v1 = *(const bf16x8*)(V + g + C);
                #pragma unroll
                for (int i = 0; i < 8; ++i) {
                    unsigned pk = (unsigned short)v0[i] | ((unsigned)(unsigned short)v1[i] << 16);
                    *(unsigned*)&VT[c8 + i][r0] = pk;
                }
            }
            if (tid < 64)
                maskf[tid] = tmask[b * T + kt * 64 + tid] ? 0.0f : NEG_INF;
            __syncthreads();

            // S^T = K Q^T
            f32x4 sacc[4] = {};
            #pragma unroll
            for (int j = 0; j < 4; ++j) {
                bf16x8 ka0 = *(const bf16x8*)&Kl[j * 16 + lc][quad * 8];
                bf16x8 ka1 = *(const bf16x8*)&Kl[j * 16 + lc][32 + quad * 8];
                sacc[j] = __builtin_amdgcn_mfma_f32_16x16x32_bf16(ka0, qb0, sacc[j], 0, 0, 0);
                sacc[j] = __builtin_amdgcn_mfma_f32_16x16x32_bf16(ka1, qb1, sacc[j], 0, 0, 0);
            }

            // t = sacc*CSC + mask (exp2 domain); causal only on diagonal tile
            float s[4][4];
            float mx = NEG_INF;
            #pragma unroll
            for (int j = 0; j < 4; ++j) {
                f32x4 mk = *(const f32x4*)&maskf[j * 16 + quad * 4];
                #pragma unroll
                for (int r = 0; r < 4; ++r) {
                    float sv = fmaf(sacc[j][r], CSC, mk[r]);
                    if (DIAG) {
                        int kg = kt * 64 + j * 16 + quad * 4 + r;
                        if (kg > qg) sv = NEG_INF;
                    }
                    s[j][r] = sv;
                    mx = fmaxf(mx, sv);
                }
            }
            mx = fmaxf(mx, __shfl_xor(mx, 16, 64));
            mx = fmaxf(mx, __shfl_xor(mx, 32, 64));
            float mnew = fmaxf(m, mx);
            float alpha = EXP2F(m - mnew);
            m = mnew;
            float ps = 0.f;
            #pragma unroll
            for (int j = 0; j < 4; ++j)
                #pragma unroll
                for (int r = 0; r < 4; ++r) {
                    float p = EXP2F(s[j][r] - mnew);
                    s[j][r] = p;
                    ps += p;
                }
            ps += __shfl_xor(ps, 16, 64);
            ps += __shfl_xor(ps, 32, 64);
            l = l * alpha + ps;
            #pragma unroll
            for (int jd = 0; jd < 4; ++jd) oaccT[jd] *= alpha;

            // P rows to LDS via packed bf16 cvt (b64 writes)
            #pragma unroll
            for (int j = 0; j < 4; ++j) {
                uint2 pk;
                pk.x = pack_bf2(s[j][0], s[j][1]);
                pk.y = pack_bf2(s[j][2], s[j][3]);
                *(uint2*)&Pl[w][lc][j * 16 + quad * 4] = pk;
            }
            bf16x8 pb0 = *(const bf16x8*)&Pl[w][lc][quad * 8];
            bf16x8 pb1 = *(const bf16x8*)&Pl[w][lc][32 + quad * 8];

            // O^T += V^T P^T
            #pragma unroll
            for (int jd = 0; jd < 4; ++jd) {
                bf16x8 va0 = *(const bf16x8*)&VT[jd * 16 + lc][quad * 8];
                bf16x8 va1 = *(const bf16x8*)&VT[jd * 16 + lc][32 + quad * 8];
                oaccT[jd] = __builtin_amdgcn_mfma_f32_16x16x32_bf16(va0, pb0, oaccT[jd], 0, 0, 0);
                oaccT[jd] = __builtin_amdgcn_mfma_f32_16x16x32_bf16(va1, pb1, oaccT[jd], 0, 0, 0);
            }
        };

        #pragma unroll 1
        for (int kt = 0; kt < qt; ++kt) step(kt, false);
        step(qt, true);

        float inv = 1.0f / l;
        size_t orow = (size_t)(b * T + qt * 64 + w * 16 + lc) * C + h * 64;
        #pragma unroll
        for (int jd = 0; jd < 4; ++jd) {
            ushort4 o4;
            o4.x = f2bf(oaccT[jd][0] * inv);
            o4.y = f2bf(oaccT[jd][1] * inv);
            o4.z = f2bf(oaccT[jd][2] * inv);
            o4.w = f2bf(oaccT[jd][3] * inv);
            *(ushort4*)(O + orow + jd * 16 + quad * 4) = o4;
        }
    }
}

extern "C" void kernel_launch(void* const* d_in, const int* in_sizes, int n_in,
                              void* d_out, int out_size, void* d_ws, size_t ws_size,
                              hipStream_t stream) {
    const float* x  = (const float*)d_in[0];
    const int* tm   = (const int*)d_in[1];
    const float* wq = (const float*)d_in[2]; const float* bq = (const float*)d_in[3];
    const float* wk = (const float*)d_in[4]; const float* bk = (const float*)d_in[5];
    const float* wv = (const float*)d_in[6]; const float* bv = (const float*)d_in[7];
    const float* wp = (const float*)d_in[8]; const float* bp = (const float*)d_in[9];
    float* out = (float*)d_out;

    const int Bv = 4, Tv = 2048, Cv = 1024;
    const size_t MT = (size_t)Bv * Tv;           // 8192 rows
    const size_t XN = MT * Cv;
    const size_t WN = (size_t)Cv * Cv;

    // layout (bf16): xb | wq wk wv (contiguous = fused 3072x1024) | wp | Q K V
    unsigned short* xb  = (unsigned short*)d_ws;
    unsigned short* wqb = xb  + XN;
    unsigned short* wkb = wqb + WN;
    unsigned short* wvb = wkb + WN;
    unsigned short* wpb = wvb + WN;
    unsigned short* Qb  = wpb + WN;
    unsigned short* Kb  = Qb + XN;
    unsigned short* Vb  = Kb + XN;
    unsigned short* Ab  = xb;                    // attn output reuses xb

    cvt_f32_bf16<<<XN / 1024, 256, 0, stream>>>(x, xb, (int)XN);
    cvt4_f32_bf16<<<dim3(WN / 1024, 4), 256, 0, stream>>>(wq, wk, wv, wp, wqb, wkb, wvb, wpb, (int)WN);

    // fused QKV: logical N = 3072, weight = [wqb;wkb;wvb], out buffers Qb/Kb/Vb
    gemm_bt<<<dim3(24, 64), 256, 0, stream>>>(xb, wqb, bq, bk, bv, nullptr, Qb, (int)MT, 3072, Cv);

    attn_kernel<<<dim3(16, Bv * 16), 256, 0, stream>>>(Qb, Kb, Vb, tm, Ab);

    gemm_bt<<<dim3(8, 64), 256, 0, stream>>>(Ab, wpb, bp, bp, bp, out, nullptr, (int)MT, 1024, Cv);
}

// Round 5
// 310.156 us; speedup vs baseline: 1.1708x; 1.0019x over previous
//
#include <hip/hip_runtime.h>
#include <hip/hip_bf16.h>
#include <math.h>

typedef short bf16x8 __attribute__((ext_vector_type(8)));
typedef float f32x4 __attribute__((ext_vector_type(4)));

#if __has_builtin(__builtin_amdgcn_exp2f)
#define EXP2F(x) __builtin_amdgcn_exp2f(x)
#else
#define EXP2F(x) __expf(0.69314718056f * (x))
#endif

__device__ __forceinline__ unsigned short f2bf(float f) {
    union { float f; unsigned u; } v; v.f = f;
    unsigned r = v.u + 0x7fffu + ((v.u >> 16) & 1u);   // RNE
    return (unsigned short)(r >> 16);
}

__device__ __forceinline__ unsigned pack_bf2(float a, float b) {
    __hip_bfloat162 h = __float22bfloat162_rn(float2{a, b});
    union { __hip_bfloat162 h; unsigned u; } c; c.h = h;
    return c.u;
}

__device__ __forceinline__ void gld_lds16(const unsigned short* g, const unsigned short* l) {
    __builtin_amdgcn_global_load_lds(
        (const __attribute__((address_space(1))) void*)g,
        (__attribute__((address_space(3))) void*)l, 16, 0, 0);
}

// ---------- fp32 -> bf16 converts ----------
__global__ void cvt_f32_bf16(const float* __restrict__ src, unsigned short* __restrict__ dst, int n) {
    int i = (blockIdx.x * blockDim.x + threadIdx.x) * 4;
    if (i < n) {
        float4 f = *(const float4*)(src + i);
        ushort4 o;
        o.x = f2bf(f.x); o.y = f2bf(f.y); o.z = f2bf(f.z); o.w = f2bf(f.w);
        *(ushort4*)(dst + i) = o;
    }
}

__global__ void cvt4_f32_bf16(const float* s0, const float* s1, const float* s2, const float* s3,
                              unsigned short* d0, unsigned short* d1, unsigned short* d2,
                              unsigned short* d3, int n) {
    const float* s; unsigned short* d;
    switch (blockIdx.y) {
        case 0: s = s0; d = d0; break;
        case 1: s = s1; d = d1; break;
        case 2: s = s2; d = d2; break;
        default: s = s3; d = d3; break;
    }
    int i = (blockIdx.x * blockDim.x + threadIdx.x) * 4;
    if (i < n) {
        float4 f = *(const float4*)(s + i);
        ushort4 o;
        o.x = f2bf(f.x); o.y = f2bf(f.y); o.z = f2bf(f.z); o.w = f2bf(f.w);
        *(ushort4*)(d + i) = o;
    }
}

// token mask -> additive float (0 / -inf)
__global__ void mask_to_f(const int* __restrict__ tm, float* __restrict__ ma, int n) {
    int i = blockIdx.x * blockDim.x + threadIdx.x;
    if (i < n) ma[i] = tm[i] ? 0.0f : -__builtin_inff();
}

// ---------- GEMM: C[M,Nlog] = A[M,K] @ W[Nlog,K]^T + bias ----------
// Fused QKV (Nlog=3072): buf = n0>>10 selects Q/K/V; V (buf 2) is stored
// TRANSPOSED to vt as [b*16+h][d][t] (packed ushort4 along t) for attn DMA.
__global__ __launch_bounds__(256) void gemm_bt(
        const unsigned short* __restrict__ A, const unsigned short* __restrict__ W,
        const float* __restrict__ b0p, const float* __restrict__ b1p,
        const float* __restrict__ b2p, float* __restrict__ outF,
        unsigned short* __restrict__ outB, unsigned short* __restrict__ vt,
        int M, int Nlog, int K) {
    __shared__ __align__(16) unsigned short As[128][32];
    __shared__ __align__(16) unsigned short Ws[128][32];
    const size_t BUFS = (size_t)8192 * 1024;
    const int m0 = blockIdx.y * 128, n0 = blockIdx.x * 128;
    const int tid = threadIdx.x, lane = tid & 63, w = tid >> 6;
    const int quad = lane >> 4, lc = lane & 15;
    const int wr = (w >> 1) * 64, wc = (w & 1) * 64;
    const int sr = lane >> 2, sc = (lane & 3) * 8;

    const int buf = n0 >> 10;
    const float* bias = buf == 0 ? b0p : (buf == 1 ? b1p : b2p);

    f32x4 acc[4][4] = {};

    for (int k0 = 0; k0 < K; k0 += 32) {
        __syncthreads();
        gld_lds16(A + (size_t)(m0 + w * 32 +      sr) * K + k0 + sc, &As[w * 32     ][0]);
        gld_lds16(A + (size_t)(m0 + w * 32 + 16 + sr) * K + k0 + sc, &As[w * 32 + 16][0]);
        gld_lds16(W + (size_t)(n0 + w * 32 +      sr) * K + k0 + sc, &Ws[w * 32     ][0]);
        gld_lds16(W + (size_t)(n0 + w * 32 + 16 + sr) * K + k0 + sc, &Ws[w * 32 + 16][0]);
        __syncthreads();
        bf16x8 af[4], bw[4];
        #pragma unroll
        for (int i = 0; i < 4; ++i) af[i] = *(const bf16x8*)&As[wr + i * 16 + lc][quad * 8];
        #pragma unroll
        for (int j = 0; j < 4; ++j) bw[j] = *(const bf16x8*)&Ws[wc + j * 16 + lc][quad * 8];
        #pragma unroll
        for (int i = 0; i < 4; ++i)
            #pragma unroll
            for (int j = 0; j < 4; ++j)
                acc[i][j] = __builtin_amdgcn_mfma_f32_16x16x32_bf16(af[i], bw[j], acc[i][j], 0, 0, 0);
    }

    #pragma unroll
    for (int j = 0; j < 4; ++j) {
        int col = n0 + wc + j * 16 + lc;
        int coll = col & 1023;
        float bj = bias[coll];
        #pragma unroll
        for (int i = 0; i < 4; ++i) {
            int rowb = m0 + wr + i * 16 + quad * 4;
            if (buf == 2) {
                // V^T store: [b*16+h][d][t], t = rowb..rowb+3 contiguous (8B)
                int bb = rowb >> 11, t = rowb & 2047;
                int hh = coll >> 6, dd = coll & 63;
                ushort4 o4;
                o4.x = f2bf(acc[i][j][0] + bj);
                o4.y = f2bf(acc[i][j][1] + bj);
                o4.z = f2bf(acc[i][j][2] + bj);
                o4.w = f2bf(acc[i][j][3] + bj);
                *(ushort4*)(vt + ((size_t)(bb * 16 + hh) * 64 + dd) * 2048 + t) = o4;
            } else {
                #pragma unroll
                for (int r = 0; r < 4; ++r) {
                    float v = acc[i][j][r] + bj;
                    size_t idx = (size_t)buf * BUFS + (size_t)(rowb + r) * 1024 + coll;
                    if (outB) outB[idx] = f2bf(v);
                    else      outF[idx] = v;
                }
            }
        }
    }
}

// ---------- flash attention (S^T / O^T, DMA-staged, prefetch-pipelined) ----------
// K staged via global_load_lds (single buf, re-staged mid-step); V^T (from
// global [bh][d][t]) double-buffered. XOR chunk-swizzle (pos = c ^ (row&7))
// keeps b128 frag reads conflict-free with unpadded 128B rows.
// Paired q-tiles (p, 31-p): 1024 uniform 33-step blocks, 4/CU residency.
__global__ __launch_bounds__(256, 4) void attn_kernel(
        const unsigned short* __restrict__ Q, const unsigned short* __restrict__ K,
        const unsigned short* __restrict__ Vt, const float* __restrict__ maskadd,
        unsigned short* __restrict__ O) {
    const int T = 2048, C = 1024;
    __shared__ __align__(16) unsigned short Kl[64][64];      // 8 KB, swizzled
    __shared__ __align__(16) unsigned short Vl[2][64][64];   // 16 KB dbuf, swizzled
    __shared__ __align__(16) unsigned short Pl[4][16][72];   // 9 KB per-wave P

    const int pair = blockIdx.x;          // 0..15
    const int bn = blockIdx.y;
    const int b = bn >> 4, h = bn & 15;
    const int tid = threadIdx.x, w = tid >> 6, lane = tid & 63;
    const int quad = lane >> 4, lc = lane & 15;
    const float NEG_INF = -__builtin_inff();
    const float CSC = 0.18033688011112042f;   // 0.125 * log2(e)

    const unsigned short* Kbh = K + (size_t)b * T * C + h * 64;            // [t][1024]
    const unsigned short* Vbh = Vt + (size_t)(b * 16 + h) * 64 * 2048;     // [d][2048]

    // staging geometry: lane -> (row = lane>>3, chunk = lane&7), source chunk
    // XOR-swizzled so LDS pos (r, c) holds logical chunk c ^ (r&7)
    const int lrow = lane >> 3;
    const int swz8 = ((lane & 7) ^ (lrow & 7)) * 8;    // element offset
    const int kb0 = (quad ^ (lc & 7)) * 8;             // reader: chunk quad
    // reader chunk 4+quad == kb0 ^ 32 elements

    auto stageK = [&](int kt) {
        #pragma unroll
        for (int ch = 0; ch < 2; ++ch)
            gld_lds16(Kbh + (size_t)(kt * 64 + w * 16 + ch * 8 + lrow) * C + swz8,
                      &Kl[w * 16 + ch * 8][0]);
    };
    auto stageV = [&](int kt, int s) {
        #pragma unroll
        for (int ch = 0; ch < 2; ++ch)
            gld_lds16(Vbh + (size_t)(w * 16 + ch * 8 + lrow) * 2048 + kt * 64 + swz8,
                      &Vl[s][w * 16 + ch * 8][0]);
    };

    #pragma unroll 1
    for (int half = 0; half < 2; ++half) {
        const int qt = half ? (31 - pair) : pair;

        if (half) __syncthreads();        // protect buffers from late readers
        stageK(0);
        stageV(0, 0);

        size_t qrow = (size_t)(b * T + qt * 64 + w * 16 + lc) * C + h * 64;
        bf16x8 qb0 = *(const bf16x8*)(Q + qrow + quad * 8);
        bf16x8 qb1 = *(const bf16x8*)(Q + qrow + 32 + quad * 8);

        f32x4 oaccT[4] = {};                  // [jd]: d = jd*16+quad*4+r, q = lc
        float m = NEG_INF, l = 0.f;
        const int qg = qt * 64 + w * 16 + lc;

        #pragma unroll 1
        for (int kt = 0; kt <= qt; ++kt) {
            const int slot = kt & 1;
            __syncthreads();              // A: K/V for kt landed (vmcnt drained)

            f32x4 mk[4];
            #pragma unroll
            for (int j = 0; j < 4; ++j)
                mk[j] = *(const f32x4*)(maskadd + b * T + kt * 64 + j * 16 + quad * 4);

            // S^T = K Q^T
            f32x4 sacc[4] = {};
            #pragma unroll
            for (int j = 0; j < 4; ++j) {
                bf16x8 ka0 = *(const bf16x8*)&Kl[j * 16 + lc][kb0];
                bf16x8 ka1 = *(const bf16x8*)&Kl[j * 16 + lc][kb0 ^ 32];
                sacc[j] = __builtin_amdgcn_mfma_f32_16x16x32_bf16(ka0, qb0, sacc[j], 0, 0, 0);
                sacc[j] = __builtin_amdgcn_mfma_f32_16x16x32_bf16(ka1, qb1, sacc[j], 0, 0, 0);
            }

            __syncthreads();              // B: all waves done reading Kl
            if (kt < qt) {                // prefetch next tiles during compute
                stageK(kt + 1);
                stageV(kt + 1, slot ^ 1);
            }

            // scale + token mask (additive); causal only on diagonal tile
            float s[4][4];
            float mx = NEG_INF;
            #pragma unroll
            for (int j = 0; j < 4; ++j) {
                #pragma unroll
                for (int r = 0; r < 4; ++r) {
                    float sv = fmaf(sacc[j][r], CSC, mk[j][r]);
                    if (kt == qt) {
                        int kg = kt * 64 + j * 16 + quad * 4 + r;
                        if (kg > qg) sv = NEG_INF;
                    }
                    s[j][r] = sv;
                    mx = fmaxf(mx, sv);
                }
            }
            mx = fmaxf(mx, __shfl_xor(mx, 16, 64));
            mx = fmaxf(mx, __shfl_xor(mx, 32, 64));
            float mnew = fmaxf(m, mx);
            float alpha = EXP2F(m - mnew);
            m = mnew;
            float ps = 0.f;
            #pragma unroll
            for (int j = 0; j < 4; ++j)
                #pragma unroll
                for (int r = 0; r < 4; ++r) {
                    float p = EXP2F(s[j][r] - mnew);
                    s[j][r] = p;
                    ps += p;
                }
            ps += __shfl_xor(ps, 16, 64);
            ps += __shfl_xor(ps, 32, 64);
            l = l * alpha + ps;
            #pragma unroll
            for (int jd = 0; jd < 4; ++jd) oaccT[jd] *= alpha;

            // P rows to per-wave LDS (packed b64 writes) then B-frags (b128)
            #pragma unroll
            for (int j = 0; j < 4; ++j) {
                uint2 pk;
                pk.x = pack_bf2(s[j][0], s[j][1]);
                pk.y = pack_bf2(s[j][2], s[j][3]);
                *(uint2*)&Pl[w][lc][j * 16 + quad * 4] = pk;
            }
            bf16x8 pb0 = *(const bf16x8*)&Pl[w][lc][quad * 8];
            bf16x8 pb1 = *(const bf16x8*)&Pl[w][lc][32 + quad * 8];

            // O^T += V^T P^T (V^T tile rows = d, swizzled chunks)
            #pragma unroll
            for (int jd = 0; jd < 4; ++jd) {
                bf16x8 va0 = *(const bf16x8*)&Vl[slot][jd * 16 + lc][kb0];
                bf16x8 va1 = *(const bf16x8*)&Vl[slot][jd * 16 + lc][kb0 ^ 32];
                oaccT[jd] = __builtin_amdgcn_mfma_f32_16x16x32_bf16(va0, pb0, oaccT[jd], 0, 0, 0);
                oaccT[jd] = __builtin_amdgcn_mfma_f32_16x16x32_bf16(va1, pb1, oaccT[jd], 0, 0, 0);
            }
        }

        // epilogue: q = lc per lane; 8B stores along d
        float inv = 1.0f / l;
        size_t orow = (size_t)(b * T + qt * 64 + w * 16 + lc) * C + h * 64;
        #pragma unroll
        for (int jd = 0; jd < 4; ++jd) {
            ushort4 o4;
            o4.x = f2bf(oaccT[jd][0] * inv);
            o4.y = f2bf(oaccT[jd][1] * inv);
            o4.z = f2bf(oaccT[jd][2] * inv);
            o4.w = f2bf(oaccT[jd][3] * inv);
            *(ushort4*)(O + orow + jd * 16 + quad * 4) = o4;
        }
    }
}

extern "C" void kernel_launch(void* const* d_in, const int* in_sizes, int n_in,
                              void* d_out, int out_size, void* d_ws, size_t ws_size,
                              hipStream_t stream) {
    const float* x  = (const float*)d_in[0];
    const int* tm   = (const int*)d_in[1];
    const float* wq = (const float*)d_in[2]; const float* bq = (const float*)d_in[3];
    const float* wk = (const float*)d_in[4]; const float* bk = (const float*)d_in[5];
    const float* wv = (const float*)d_in[6]; const float* bv = (const float*)d_in[7];
    const float* wp = (const float*)d_in[8]; const float* bp = (const float*)d_in[9];
    float* out = (float*)d_out;

    const int Bv = 4, Tv = 2048, Cv = 1024;
    const size_t MT = (size_t)Bv * Tv;           // 8192 rows
    const size_t XN = MT * Cv;
    const size_t WN = (size_t)Cv * Cv;

    // layout (bf16): xb | wq wk wv (fused 3072x1024) | wp | Q | K | Vt
    unsigned short* xb  = (unsigned short*)d_ws;
    unsigned short* wqb = xb  + XN;
    unsigned short* wkb = wqb + WN;
    unsigned short* wvb = wkb + WN;
    unsigned short* wpb = wvb + WN;
    unsigned short* Qb  = wpb + WN;
    unsigned short* Kb  = Qb + XN;
    unsigned short* Vtb = Kb + XN;               // transposed V [bh][d][t]
    unsigned short* Ab  = xb;                    // attn output reuses xb
    // maskadd scratch lives at the start of d_out (fully overwritten by the
    // final projection AFTER attn completes; stream-ordered => safe)
    float* maskadd = (float*)d_out;

    cvt_f32_bf16<<<XN / 1024, 256, 0, stream>>>(x, xb, (int)XN);
    cvt4_f32_bf16<<<dim3(WN / 1024, 4), 256, 0, stream>>>(wq, wk, wv, wp, wqb, wkb, wvb, wpb, (int)WN);
    mask_to_f<<<(int)(MT / 256), 256, 0, stream>>>(tm, maskadd, (int)MT);

    // fused QKV: logical N = 3072; V portion stored transposed into Vtb
    gemm_bt<<<dim3(24, 64), 256, 0, stream>>>(xb, wqb, bq, bk, bv, nullptr, Qb, Vtb, (int)MT, 3072, Cv);

    attn_kernel<<<dim3(16, Bv * 16), 256, 0, stream>>>(Qb, Kb, Vtb, maskadd, Ab);

    gemm_bt<<<dim3(8, 64), 256, 0, stream>>>(Ab, wpb, bp, bp, bp, out, nullptr, nullptr, (int)MT, 1024, Cv);
}

// Round 6
// 304.298 us; speedup vs baseline: 1.1934x; 1.0192x over previous
//
#include <hip/hip_runtime.h>
#include <hip/hip_bf16.h>
#include <math.h>

typedef short bf16x8 __attribute__((ext_vector_type(8)));
typedef float f32x4 __attribute__((ext_vector_type(4)));

#if __has_builtin(__builtin_amdgcn_exp2f)
#define EXP2F(x) __builtin_amdgcn_exp2f(x)
#else
#define EXP2F(x) __expf(0.69314718056f * (x))
#endif

__device__ __forceinline__ unsigned short f2bf(float f) {
    union { float f; unsigned u; } v; v.f = f;
    unsigned r = v.u + 0x7fffu + ((v.u >> 16) & 1u);   // RNE
    return (unsigned short)(r >> 16);
}

__device__ __forceinline__ unsigned pack_bf2(float a, float b) {
    __hip_bfloat162 h = __float22bfloat162_rn(float2{a, b});
    union { __hip_bfloat162 h; unsigned u; } c; c.h = h;
    return c.u;
}

__device__ __forceinline__ void gld_lds16(const unsigned short* g, const unsigned short* l) {
    __builtin_amdgcn_global_load_lds(
        (const __attribute__((address_space(1))) void*)g,
        (__attribute__((address_space(3))) void*)l, 16, 0, 0);
}

// ---------- fp32 -> bf16 converts ----------
__global__ void cvt_f32_bf16(const float* __restrict__ src, unsigned short* __restrict__ dst, int n) {
    int i = (blockIdx.x * blockDim.x + threadIdx.x) * 4;
    if (i < n) {
        float4 f = *(const float4*)(src + i);
        ushort4 o;
        o.x = f2bf(f.x); o.y = f2bf(f.y); o.z = f2bf(f.z); o.w = f2bf(f.w);
        *(ushort4*)(dst + i) = o;
    }
}

__global__ void cvt4_f32_bf16(const float* s0, const float* s1, const float* s2, const float* s3,
                              unsigned short* d0, unsigned short* d1, unsigned short* d2,
                              unsigned short* d3, int n) {
    const float* s; unsigned short* d;
    switch (blockIdx.y) {
        case 0: s = s0; d = d0; break;
        case 1: s = s1; d = d1; break;
        case 2: s = s2; d = d2; break;
        default: s = s3; d = d3; break;
    }
    int i = (blockIdx.x * blockDim.x + threadIdx.x) * 4;
    if (i < n) {
        float4 f = *(const float4*)(s + i);
        ushort4 o;
        o.x = f2bf(f.x); o.y = f2bf(f.y); o.z = f2bf(f.z); o.w = f2bf(f.w);
        *(ushort4*)(d + i) = o;
    }
}

// token mask -> additive float (0 / -inf)
__global__ void mask_to_f(const int* __restrict__ tm, float* __restrict__ ma, int n) {
    int i = blockIdx.x * blockDim.x + threadIdx.x;
    if (i < n) ma[i] = tm[i] ? 0.0f : -__builtin_inff();
}

// ---------- GEMM: C[M,Nlog] = A[M,K] @ W[Nlog,K]^T + bias ----------
// Double-buffered LDS + single barrier per K-iter: sync (cur landed) ->
// issue DMA for next into alt -> compute cur. Loads overlap full compute.
// Fused QKV (Nlog=3072): buf = n0>>10 selects Q/K/V; V (buf 2) stored
// TRANSPOSED to vt as [b*16+h][d][t] (packed ushort4 along t) for attn DMA.
__global__ __launch_bounds__(256, 4) void gemm_bt(
        const unsigned short* __restrict__ A, const unsigned short* __restrict__ W,
        const float* __restrict__ b0p, const float* __restrict__ b1p,
        const float* __restrict__ b2p, float* __restrict__ outF,
        unsigned short* __restrict__ outB, unsigned short* __restrict__ vt,
        int M, int Nlog, int K) {
    __shared__ __align__(16) unsigned short As[2][128][32];   // 8 KB x2
    __shared__ __align__(16) unsigned short Ws[2][128][32];   // 8 KB x2
    const size_t BUFS = (size_t)8192 * 1024;
    const int m0 = blockIdx.y * 128, n0 = blockIdx.x * 128;
    const int tid = threadIdx.x, lane = tid & 63, w = tid >> 6;
    const int quad = lane >> 4, lc = lane & 15;
    const int wr = (w >> 1) * 64, wc = (w & 1) * 64;
    const int sr = lane >> 2, sc = (lane & 3) * 8;

    const int buf = n0 >> 10;
    const float* bias = buf == 0 ? b0p : (buf == 1 ? b1p : b2p);

    auto stage = [&](int s, int k0) {
        gld_lds16(A + (size_t)(m0 + w * 32 +      sr) * K + k0 + sc, &As[s][w * 32     ][0]);
        gld_lds16(A + (size_t)(m0 + w * 32 + 16 + sr) * K + k0 + sc, &As[s][w * 32 + 16][0]);
        gld_lds16(W + (size_t)(n0 + w * 32 +      sr) * K + k0 + sc, &Ws[s][w * 32     ][0]);
        gld_lds16(W + (size_t)(n0 + w * 32 + 16 + sr) * K + k0 + sc, &Ws[s][w * 32 + 16][0]);
    };

    f32x4 acc[4][4] = {};
    stage(0, 0);

    for (int k0 = 0; k0 < K; k0 += 32) {
        const int cur = (k0 >> 5) & 1;
        __syncthreads();                       // As/Ws[cur] landed (vmcnt drain)
        if (k0 + 32 < K) stage(cur ^ 1, k0 + 32);   // lands by next sync
        bf16x8 af[4], bw[4];
        #pragma unroll
        for (int i = 0; i < 4; ++i) af[i] = *(const bf16x8*)&As[cur][wr + i * 16 + lc][quad * 8];
        #pragma unroll
        for (int j = 0; j < 4; ++j) bw[j] = *(const bf16x8*)&Ws[cur][wc + j * 16 + lc][quad * 8];
        #pragma unroll
        for (int i = 0; i < 4; ++i)
            #pragma unroll
            for (int j = 0; j < 4; ++j)
                acc[i][j] = __builtin_amdgcn_mfma_f32_16x16x32_bf16(af[i], bw[j], acc[i][j], 0, 0, 0);
    }

    #pragma unroll
    for (int j = 0; j < 4; ++j) {
        int col = n0 + wc + j * 16 + lc;
        int coll = col & 1023;
        float bj = bias[coll];
        #pragma unroll
        for (int i = 0; i < 4; ++i) {
            int rowb = m0 + wr + i * 16 + quad * 4;
            if (buf == 2) {
                // V^T store: [b*16+h][d][t], t = rowb..rowb+3 contiguous (8B)
                int bb = rowb >> 11, t = rowb & 2047;
                int hh = coll >> 6, dd = coll & 63;
                ushort4 o4;
                o4.x = f2bf(acc[i][j][0] + bj);
                o4.y = f2bf(acc[i][j][1] + bj);
                o4.z = f2bf(acc[i][j][2] + bj);
                o4.w = f2bf(acc[i][j][3] + bj);
                *(ushort4*)(vt + ((size_t)(bb * 16 + hh) * 64 + dd) * 2048 + t) = o4;
            } else {
                #pragma unroll
                for (int r = 0; r < 4; ++r) {
                    float v = acc[i][j][r] + bj;
                    size_t idx = (size_t)buf * BUFS + (size_t)(rowb + r) * 1024 + coll;
                    if (outB) outB[idx] = f2bf(v);
                    else      outF[idx] = v;
                }
            }
        }
    }
}

// ---------- flash attention (S^T / O^T, DMA-staged, prefetch-pipelined) ----------
// Unchanged from R5 (94 us): K single-buf re-staged mid-step, V^T dbuf,
// XOR chunk-swizzle, paired q-tiles (p, 31-p), 4 blocks/CU.
__global__ __launch_bounds__(256, 4) void attn_kernel(
        const unsigned short* __restrict__ Q, const unsigned short* __restrict__ K,
        const unsigned short* __restrict__ Vt, const float* __restrict__ maskadd,
        unsigned short* __restrict__ O) {
    const int T = 2048, C = 1024;
    __shared__ __align__(16) unsigned short Kl[64][64];      // 8 KB, swizzled
    __shared__ __align__(16) unsigned short Vl[2][64][64];   // 16 KB dbuf, swizzled
    __shared__ __align__(16) unsigned short Pl[4][16][72];   // 9 KB per-wave P

    const int pair = blockIdx.x;          // 0..15
    const int bn = blockIdx.y;
    const int b = bn >> 4, h = bn & 15;
    const int tid = threadIdx.x, w = tid >> 6, lane = tid & 63;
    const int quad = lane >> 4, lc = lane & 15;
    const float NEG_INF = -__builtin_inff();
    const float CSC = 0.18033688011112042f;   // 0.125 * log2(e)

    const unsigned short* Kbh = K + (size_t)b * T * C + h * 64;            // [t][1024]
    const unsigned short* Vbh = Vt + (size_t)(b * 16 + h) * 64 * 2048;     // [d][2048]

    const int lrow = lane >> 3;
    const int swz8 = ((lane & 7) ^ (lrow & 7)) * 8;    // element offset
    const int kb0 = (quad ^ (lc & 7)) * 8;             // reader chunk; ^32 = upper half

    auto stageK = [&](int kt) {
        #pragma unroll
        for (int ch = 0; ch < 2; ++ch)
            gld_lds16(Kbh + (size_t)(kt * 64 + w * 16 + ch * 8 + lrow) * C + swz8,
                      &Kl[w * 16 + ch * 8][0]);
    };
    auto stageV = [&](int kt, int s) {
        #pragma unroll
        for (int ch = 0; ch < 2; ++ch)
            gld_lds16(Vbh + (size_t)(w * 16 + ch * 8 + lrow) * 2048 + kt * 64 + swz8,
                      &Vl[s][w * 16 + ch * 8][0]);
    };

    #pragma unroll 1
    for (int half = 0; half < 2; ++half) {
        const int qt = half ? (31 - pair) : pair;

        if (half) __syncthreads();        // protect buffers from late readers
        stageK(0);
        stageV(0, 0);

        size_t qrow = (size_t)(b * T + qt * 64 + w * 16 + lc) * C + h * 64;
        bf16x8 qb0 = *(const bf16x8*)(Q + qrow + quad * 8);
        bf16x8 qb1 = *(const bf16x8*)(Q + qrow + 32 + quad * 8);

        f32x4 oaccT[4] = {};                  // [jd]: d = jd*16+quad*4+r, q = lc
        float m = NEG_INF, l = 0.f;
        const int qg = qt * 64 + w * 16 + lc;

        #pragma unroll 1
        for (int kt = 0; kt <= qt; ++kt) {
            const int slot = kt & 1;
            __syncthreads();              // A: K/V for kt landed (vmcnt drained)

            f32x4 mk[4];
            #pragma unroll
            for (int j = 0; j < 4; ++j)
                mk[j] = *(const f32x4*)(maskadd + b * T + kt * 64 + j * 16 + quad * 4);

            // S^T = K Q^T
            f32x4 sacc[4] = {};
            #pragma unroll
            for (int j = 0; j < 4; ++j) {
                bf16x8 ka0 = *(const bf16x8*)&Kl[j * 16 + lc][kb0];
                bf16x8 ka1 = *(const bf16x8*)&Kl[j * 16 + lc][kb0 ^ 32];
                sacc[j] = __builtin_amdgcn_mfma_f32_16x16x32_bf16(ka0, qb0, sacc[j], 0, 0, 0);
                sacc[j] = __builtin_amdgcn_mfma_f32_16x16x32_bf16(ka1, qb1, sacc[j], 0, 0, 0);
            }

            __syncthreads();              // B: all waves done reading Kl
            if (kt < qt) {                // prefetch next tiles during compute
                stageK(kt + 1);
                stageV(kt + 1, slot ^ 1);
            }

            // scale + token mask (additive); causal only on diagonal tile
            float s[4][4];
            float mx = NEG_INF;
            #pragma unroll
            for (int j = 0; j < 4; ++j) {
                #pragma unroll
                for (int r = 0; r < 4; ++r) {
                    float sv = fmaf(sacc[j][r], CSC, mk[j][r]);
                    if (kt == qt) {
                        int kg = kt * 64 + j * 16 + quad * 4 + r;
                        if (kg > qg) sv = NEG_INF;
                    }
                    s[j][r] = sv;
                    mx = fmaxf(mx, sv);
                }
            }
            mx = fmaxf(mx, __shfl_xor(mx, 16, 64));
            mx = fmaxf(mx, __shfl_xor(mx, 32, 64));
            float mnew = fmaxf(m, mx);
            float alpha = EXP2F(m - mnew);
            m = mnew;
            float ps = 0.f;
            #pragma unroll
            for (int j = 0; j < 4; ++j)
                #pragma unroll
                for (int r = 0; r < 4; ++r) {
                    float p = EXP2F(s[j][r] - mnew);
                    s[j][r] = p;
                    ps += p;
                }
            ps += __shfl_xor(ps, 16, 64);
            ps += __shfl_xor(ps, 32, 64);
            l = l * alpha + ps;
            #pragma unroll
            for (int jd = 0; jd < 4; ++jd) oaccT[jd] *= alpha;

            // P rows to per-wave LDS (packed b64 writes) then B-frags (b128)
            #pragma unroll
            for (int j = 0; j < 4; ++j) {
                uint2 pk;
                pk.x = pack_bf2(s[j][0], s[j][1]);
                pk.y = pack_bf2(s[j][2], s[j][3]);
                *(uint2*)&Pl[w][lc][j * 16 + quad * 4] = pk;
            }
            bf16x8 pb0 = *(const bf16x8*)&Pl[w][lc][quad * 8];
            bf16x8 pb1 = *(const bf16x8*)&Pl[w][lc][32 + quad * 8];

            // O^T += V^T P^T (V^T tile rows = d, swizzled chunks)
            #pragma unroll
            for (int jd = 0; jd < 4; ++jd) {
                bf16x8 va0 = *(const bf16x8*)&Vl[slot][jd * 16 + lc][kb0];
                bf16x8 va1 = *(const bf16x8*)&Vl[slot][jd * 16 + lc][kb0 ^ 32];
                oaccT[jd] = __builtin_amdgcn_mfma_f32_16x16x32_bf16(va0, pb0, oaccT[jd], 0, 0, 0);
                oaccT[jd] = __builtin_amdgcn_mfma_f32_16x16x32_bf16(va1, pb1, oaccT[jd], 0, 0, 0);
            }
        }

        // epilogue: q = lc per lane; 8B stores along d
        float inv = 1.0f / l;
        size_t orow = (size_t)(b * T + qt * 64 + w * 16 + lc) * C + h * 64;
        #pragma unroll
        for (int jd = 0; jd < 4; ++jd) {
            ushort4 o4;
            o4.x = f2bf(oaccT[jd][0] * inv);
            o4.y = f2bf(oaccT[jd][1] * inv);
            o4.z = f2bf(oaccT[jd][2] * inv);
            o4.w = f2bf(oaccT[jd][3] * inv);
            *(ushort4*)(O + orow + jd * 16 + quad * 4) = o4;
        }
    }
}

extern "C" void kernel_launch(void* const* d_in, const int* in_sizes, int n_in,
                              void* d_out, int out_size, void* d_ws, size_t ws_size,
                              hipStream_t stream) {
    const float* x  = (const float*)d_in[0];
    const int* tm   = (const int*)d_in[1];
    const float* wq = (const float*)d_in[2]; const float* bq = (const float*)d_in[3];
    const float* wk = (const float*)d_in[4]; const float* bk = (const float*)d_in[5];
    const float* wv = (const float*)d_in[6]; const float* bv = (const float*)d_in[7];
    const float* wp = (const float*)d_in[8]; const float* bp = (const float*)d_in[9];
    float* out = (float*)d_out;

    const int Bv = 4, Tv = 2048, Cv = 1024;
    const size_t MT = (size_t)Bv * Tv;           // 8192 rows
    const size_t XN = MT * Cv;
    const size_t WN = (size_t)Cv * Cv;

    // layout (bf16): xb | wq wk wv (fused 3072x1024) | wp | Q | K | Vt
    unsigned short* xb  = (unsigned short*)d_ws;
    unsigned short* wqb = xb  + XN;
    unsigned short* wkb = wqb + WN;
    unsigned short* wvb = wkb + WN;
    unsigned short* wpb = wvb + WN;
    unsigned short* Qb  = wpb + WN;
    unsigned short* Kb  = Qb + XN;
    unsigned short* Vtb = Kb + XN;               // transposed V [bh][d][t]
    unsigned short* Ab  = xb;                    // attn output reuses xb
    // maskadd scratch lives at the start of d_out (overwritten by the final
    // projection only after attn completes; stream-ordered => safe)
    float* maskadd = (float*)d_out;

    cvt_f32_bf16<<<XN / 1024, 256, 0, stream>>>(x, xb, (int)XN);
    cvt4_f32_bf16<<<dim3(WN / 1024, 4), 256, 0, stream>>>(wq, wk, wv, wp, wqb, wkb, wvb, wpb, (int)WN);
    mask_to_f<<<(int)(MT / 256), 256, 0, stream>>>(tm, maskadd, (int)MT);

    // fused QKV: logical N = 3072; V portion stored transposed into Vtb
    gemm_bt<<<dim3(24, 64), 256, 0, stream>>>(xb, wqb, bq, bk, bv, nullptr, Qb, Vtb, (int)MT, 3072, Cv);

    attn_kernel<<<dim3(16, Bv * 16), 256, 0, stream>>>(Qb, Kb, Vtb, maskadd, Ab);

    gemm_bt<<<dim3(8, 64), 256, 0, stream>>>(Ab, wpb, bp, bp, bp, out, nullptr, nullptr, (int)MT, 1024, Cv);
}